// Round 7
// baseline (316.276 us; speedup 1.0000x reference)
//
#include <hip/hip_runtime.h>

typedef unsigned char u8;
typedef float f32x4 __attribute__((ext_vector_type(4)));
typedef _Float16 f16x8 __attribute__((ext_vector_type(8)));

#define DIM 128

__device__ __forceinline__ float fast_tanh(float x) {
    // tanh(x) = 1 - 2/(exp2(2x*log2e)+1); exact +-1 saturation via inf->0
    float e = __builtin_amdgcn_exp2f(x * 2.885390081777927f);
    return 1.0f - 2.0f * __builtin_amdgcn_rcpf(e + 1.0f);
}
__device__ __forceinline__ float fast_sigmoid(float x) {
    float e = __builtin_amdgcn_exp2f(x * -1.4426950408889634f);
    return __builtin_amdgcn_rcpf(1.0f + e);
}

// stage W2^T (fp16, XOR-swizzled 16B chunks) into LDS; call with 512 threads
__device__ __forceinline__ void stage_w2(const float* __restrict__ W2,
                                         _Float16* sW2T, int tid) {
    #pragma unroll
    for (int s = 0; s < 4; ++s) {
        int chunk = s * 512 + tid;       // 0..2047
        int n = chunk & 127, ko = chunk >> 7;
        f16x8 v;
        #pragma unroll
        for (int qq = 0; qq < 8; ++qq)
            v[qq] = (_Float16)W2[(ko * 8 + qq) * DIM + n];   // coalesced over n
        int slot = ko ^ (n & 15);
        *(f16x8*)&sW2T[n * DIM + slot * 8] = v;
    }
}

// one wave evaluates 32 points (2 A-frags x 16 rows) x 128 out-dims.
// Result: rs[mf][rg] = sum_c tanh(h2+b2)*W3 (reduced across lanes; valid on all).
// C/D layout: point-row = mf*16 + lg*4 + rg.
__device__ __forceinline__ void mlp_wave(
    const float xs[2], const float ys[2], const _Float16* sW2T,
    const float* __restrict__ W1, const float* __restrict__ b1,
    const float* __restrict__ b2, const float* __restrict__ W3,
    int lg, int l15, float rs[2][4])
{
    f32x4 acc[2][8];
    #pragma unroll
    for (int mf = 0; mf < 2; ++mf)
        #pragma unroll
        for (int nf = 0; nf < 8; ++nf) acc[mf][nf] = (f32x4)(0.0f);

    #pragma unroll
    for (int kf = 0; kf < 4; ++kf) {
        const int kbase = kf * 32 + lg * 8;
        f16x8 bh[8];
        #pragma unroll
        for (int nf = 0; nf < 8; ++nf) {
            int cc = nf * 16 + l15;
            int slot = (kf * 4 + lg) ^ l15;   // matches stage_w2 swizzle (cc&15==l15)
            bh[nf] = *(const f16x8*)&sW2T[cc * DIM + slot * 8];
        }
        f32x4 wxa = *(const f32x4*)&W1[kbase];
        f32x4 wxb = *(const f32x4*)&W1[kbase + 4];
        f32x4 wya = *(const f32x4*)&W1[DIM + kbase];
        f32x4 wyb = *(const f32x4*)&W1[DIM + kbase + 4];
        f32x4 b1a = *(const f32x4*)&b1[kbase];
        f32x4 b1b = *(const f32x4*)&b1[kbase + 4];
        f16x8 ah[2];
        #pragma unroll
        for (int mf = 0; mf < 2; ++mf) {
            float x = xs[mf], y = ys[mf];
            #pragma unroll
            for (int qq = 0; qq < 4; ++qq)
                ah[mf][qq] = (_Float16)fast_tanh(fmaf(x, wxa[qq], fmaf(y, wya[qq], b1a[qq])));
            #pragma unroll
            for (int qq = 0; qq < 4; ++qq)
                ah[mf][4 + qq] = (_Float16)fast_tanh(fmaf(x, wxb[qq], fmaf(y, wyb[qq], b1b[qq])));
        }
        #pragma unroll
        for (int nf = 0; nf < 8; ++nf)
            #pragma unroll
            for (int mf = 0; mf < 2; ++mf)
                acc[mf][nf] = __builtin_amdgcn_mfma_f32_16x16x32_f16(ah[mf], bh[nf], acc[mf][nf], 0, 0, 0);
    }

    #pragma unroll
    for (int mf = 0; mf < 2; ++mf)
        #pragma unroll
        for (int rg = 0; rg < 4; ++rg) rs[mf][rg] = 0.0f;
    #pragma unroll
    for (int nf = 0; nf < 8; ++nf) {
        int cc = nf * 16 + l15;
        float w3v = W3[cc], b2v = b2[cc];
        #pragma unroll
        for (int mf = 0; mf < 2; ++mf)
            #pragma unroll
            for (int rg = 0; rg < 4; ++rg)
                rs[mf][rg] += fast_tanh(acc[mf][nf][rg] + b2v) * w3v;
    }
    #pragma unroll
    for (int mf = 0; mf < 2; ++mf)
        #pragma unroll
        for (int rg = 0; rg < 4; ++rg) {
            float v = rs[mf][rg];
            v += __shfl_xor(v, 1);
            v += __shfl_xor(v, 2);
            v += __shfl_xor(v, 4);
            v += __shfl_xor(v, 8);
            rs[mf][rg] = v;
        }
}

// ---- dense eval of the 33x33 base grid (5 blocks x 256 points) ----
__global__ __launch_bounds__(512, 4) void eval_base(
    const float* __restrict__ W1, const float* __restrict__ b1,
    const float* __restrict__ W2, const float* __restrict__ b2,
    const float* __restrict__ W3, const float* __restrict__ b3,
    const float* __restrict__ bmin, const float* __restrict__ bmax,
    float* __restrict__ out)
{
    __shared__ __align__(16) _Float16 sW2T[DIM * DIM];
    const int R = 33, N = 1089;
    const int tid = threadIdx.x;
    stage_w2(W2, sW2T, tid);

    const int w = tid >> 6, lane = tid & 63;
    const int l15 = lane & 15, lg = lane >> 4;
    const int m0 = blockIdx.x * 256;
    const float inv = 1.0f / 32.0f;
    const float bx0 = bmin[0], by0 = bmin[1];
    const float sx = bmax[0] - bx0, sy = bmax[1] - by0;
    float xs[2], ys[2];
    #pragma unroll
    for (int mf = 0; mf < 2; ++mf) {
        int pi = m0 + w * 32 + mf * 16 + l15;
        int pg = (pi < N) ? pi : N - 1;
        int gi = pg / R, gj = pg - gi * R;
        xs[mf] = bx0 + (float)gj * inv * sx;
        ys[mf] = by0 + (float)gi * inv * sy;
    }
    __syncthreads();

    float rs[2][4];
    mlp_wave(xs, ys, sW2T, W1, b1, b2, W3, lg, l15, rs);
    if (l15 == 0) {
        float b3v = b3[0];
        #pragma unroll
        for (int mf = 0; mf < 2; ++mf)
            #pragma unroll
            for (int rg = 0; rg < 4; ++rg) {
                int po = m0 + w * 32 + mf * 16 + lg * 4 + rg;
                if (po < N) out[po] = fast_sigmoid(rs[mf][rg] + b3v);
            }
    }
}

// ---- fused level: upsample + raw + SPARSE in-tile MLP eval + resolve ----
// q is only read at boundary|cand cells, all within dilate^4(raw) & ~calc0:
// build that worklist locally, evaluate only those points.
#define TS 32
#define HW 40   // TS + 2*4 halo
#define NT 512
__global__ __launch_bounds__(NT, 4) void level_fused(
    const float* __restrict__ occP, const u8* __restrict__ calcP, int Rp,
    float* __restrict__ occOut, u8* __restrict__ calcOut, int R,
    const float* __restrict__ W1, const float* __restrict__ b1,
    const float* __restrict__ W2, const float* __restrict__ b2,
    const float* __restrict__ W3, const float* __restrict__ b3,
    const float* __restrict__ bmin, const float* __restrict__ bmax)
{
    __shared__ float sOcc[HW * HW], sQ[HW * HW];
    __shared__ u8 sRaw[HW * HW], sCalc[HW * HW], sCfA[HW * HW], sCfB[HW * HW];
    __shared__ __align__(16) _Float16 sW2T[DIM * DIM];
    __shared__ unsigned short sWl[HW * HW];
    __shared__ int sCnt;

    const int nT = (R + TS - 1) / TS;
    const int bi = blockIdx.x / nT, bj = blockIdx.x - bi * nT;
    const int fi0 = bi * TS - 4, fj0 = bj * TS - 4;
    const int tid = threadIdx.x;
    const float BAL = 0.5f;
    if (tid == 0) sCnt = 0;

    // phase 1: upsample occ + raw-boundary + inherited calc (NO q)
    bool anyRaw = false;
    for (int c = tid; c < HW * HW; c += NT) {
        int li = c / HW, lj = c - li * HW;
        int fi = fi0 + li, fj = fj0 + lj;
        float occi = 0.5f; u8 rw = 0, cal = 0;
        if (fi >= 0 && fi < R && fj >= 0 && fj < R) {
            int ip = fi >> 1, jp = fj >> 1;
            float tl = occP[ip * Rp + jp];
            int oi = fi & 1, oj = fj & 1;
            bool b;
            if (!oi && !oj) { occi = tl; b = false; }
            else if (oi && !oj) {
                float bl = occP[(ip + 1) * Rp + jp];
                occi = 0.5f * (tl + bl);
                b = (tl > BAL) != (bl > BAL);
            } else if (!oi && oj) {
                float tr = occP[ip * Rp + jp + 1];
                occi = 0.5f * (tl + tr);
                b = (tl > BAL) != (tr > BAL);
            } else {
                float bl = occP[(ip + 1) * Rp + jp];
                float tr = occP[ip * Rp + jp + 1];
                float br = occP[(ip + 1) * Rp + jp + 1];
                occi = 0.5f * (0.5f * (tl + bl) + 0.5f * (tr + br)); // exact _up2 order
                bool m0 = tl > BAL, m1 = bl > BAL, m2 = tr > BAL, m3 = br > BAL;
                b = (m0 | m1 | m2 | m3) && !(m0 & m1 & m2 & m3);
            }
            rw = b ? 1 : 0;
            if (((fi | fj) & 1) == 0) cal = calcP ? calcP[ip * Rp + jp] : 1;
        }
        sOcc[c] = occi; sRaw[c] = rw; sCalc[c] = cal;
        anyRaw |= (rw != 0);
    }

    if (!__syncthreads_or(anyRaw ? 1 : 0)) {
        // pure write-through: no boundary anywhere near this tile
        for (int c = tid; c < HW * HW; c += NT) {
            int li = c / HW, lj = c - li * HW;
            if (li < 4 || li >= HW - 4 || lj < 4 || lj >= HW - 4) continue;
            int fi = fi0 + li, fj = fj0 + lj;
            if (fi < 0 || fi >= R || fj < 0 || fj >= R) continue;
            occOut[fi * R + fj] = sOcc[c];
            calcOut[fi * R + fj] = sCalc[c];
        }
        return;
    }

    // need-mask = dilate^4(raw): separable or-pass. rows -> sCfB
    for (int c = tid; c < HW * HW; c += NT) {
        int li = c / HW, lj = c - li * HW;
        int j0 = lj - 4 < 0 ? 0 : lj - 4, j1 = lj + 4 > HW - 1 ? HW - 1 : lj + 4;
        u8 a = 0;
        for (int jj = j0; jj <= j1; ++jj) a |= sRaw[li * HW + jj];
        sCfB[c] = a;
    }
    __syncthreads();
    // cols + build worklist (skip already-calc'd cells: they never read q)
    for (int c = tid; c < HW * HW; c += NT) {
        int li = c / HW, lj = c - li * HW;
        int i0 = li - 4 < 0 ? 0 : li - 4, i1 = li + 4 > HW - 1 ? HW - 1 : li + 4;
        u8 a = 0;
        for (int ii = i0; ii <= i1; ++ii) a |= sCfB[ii * HW + lj];
        int fi = fi0 + li, fj = fj0 + lj;
        if (a && !sCalc[c] && fi >= 0 && fi < R && fj >= 0 && fj < R) {
            int idx = atomicAdd(&sCnt, 1);
            sWl[idx] = (unsigned short)c;
        }
    }
    __syncthreads();
    // zero conflict buffers (sCfB was the dilate temp) + stage W2
    for (int c = tid; c < HW * HW; c += NT) { sCfA[c] = 0; sCfB[c] = 0; }
    stage_w2(W2, sW2T, tid);
    __syncthreads();

    // sparse MLP eval over the worklist, 256 points per round
    {
        const int w = tid >> 6, lane = tid & 63;
        const int l15 = lane & 15, lg = lane >> 4;
        const float inv = 1.0f / (float)(R - 1);   // R-1 pow2 -> exact
        const float bx0 = bmin[0], by0 = bmin[1];
        const float sx = bmax[0] - bx0, sy = bmax[1] - by0;
        const int cnt = sCnt;
        const int rounds = (cnt + 255) >> 8;
        for (int rd = 0; rd < rounds; ++rd) {
            const int base = rd * 256 + w * 32;
            float xs[2], ys[2];
            #pragma unroll
            for (int mf = 0; mf < 2; ++mf) {
                int gidx = base + mf * 16 + l15;
                int cell = (gidx < cnt) ? sWl[gidx] : 0;
                int li = cell / HW, lj = cell - li * HW;
                xs[mf] = bx0 + (float)(fj0 + lj) * inv * sx;
                ys[mf] = by0 + (float)(fi0 + li) * inv * sy;
            }
            float rs[2][4];
            mlp_wave(xs, ys, sW2T, W1, b1, b2, W3, lg, l15, rs);
            if (l15 == 0) {
                float b3v = b3[0];
                #pragma unroll
                for (int mf = 0; mf < 2; ++mf)
                    #pragma unroll
                    for (int rg = 0; rg < 4; ++rg) {
                        int gidx = base + mf * 16 + lg * 4 + rg;
                        if (gidx < cnt)
                            sQ[sWl[gidx]] = fast_sigmoid(rs[mf][rg] + b3v);
                    }
            }
        }
    }
    __syncthreads();

    // phase 2: boundary = any3x3(raw) & ~calc; seed conflicts; occ select
    bool anyCf = false;
    for (int c = tid; c < HW * HW; c += NT) {
        int li = c / HW, lj = c - li * HW;
        if (li < 1 || li >= HW - 1 || lj < 1 || lj >= HW - 1) continue;
        int fi = fi0 + li, fj = fj0 + lj;
        if (fi < 0 || fi >= R || fj < 0 || fj >= R) continue;
        bool b = false;
        #pragma unroll
        for (int di = -1; di <= 1; ++di)
            #pragma unroll
            for (int dj = -1; dj <= 1; ++dj)
                if (sRaw[(li + di) * HW + (lj + dj)]) b = true;
        b = b && !sCalc[c];
        float oi = sOcc[c], qq = sQ[c];
        u8 cf = (b && (oi - BAL) * (qq - BAL) < 0.0f) ? 1 : 0;
        if (b) { sOcc[c] = qq; sCalc[c] = 1; }
        sCfA[c] = cf;
        anyCf |= (cf != 0);
    }
    int haveCf = __syncthreads_or(anyCf ? 1 : 0);

    // 3 conflict-propagation iterations (skip when none remain)
    for (int it = 0; it < 3 && haveCf; ++it) {
        const u8* cin = (it & 1) ? sCfB : sCfA;
        u8* cout      = (it & 1) ? sCfA : sCfB;
        int lo = 2 + it, hi = HW - 2 - it;
        bool anyNc = false;
        for (int c = tid; c < HW * HW; c += NT) {
            int li = c / HW, lj = c - li * HW;
            if (li < lo || li >= hi || lj < lo || lj >= hi) continue;
            int fi = fi0 + li, fj = fj0 + lj;
            if (fi < 0 || fi >= R || fj < 0 || fj >= R) continue;
            bool any = false;
            #pragma unroll
            for (int di = -1; di <= 1; ++di)
                #pragma unroll
                for (int dj = -1; dj <= 1; ++dj)
                    if (cin[(li + di) * HW + (lj + dj)]) any = true;
            bool cand = any && !sCalc[c];
            float oc = sOcc[c], qq = sQ[c];
            u8 nc = (cand && (oc - BAL) * (qq - BAL) < 0.0f) ? 1 : 0;
            if (cand) { sOcc[c] = qq; sCalc[c] = 1; }
            cout[c] = nc;
            anyNc |= (nc != 0);
        }
        haveCf = __syncthreads_or(anyNc ? 1 : 0);
    }

    // write core 32x32
    for (int c = tid; c < HW * HW; c += NT) {
        int li = c / HW, lj = c - li * HW;
        if (li < 4 || li >= HW - 4 || lj < 4 || lj >= HW - 4) continue;
        int fi = fi0 + li, fj = fj0 + lj;
        if (fi < 0 || fi >= R || fj < 0 || fj >= R) continue;
        occOut[fi * R + fj] = sOcc[c];
        calcOut[fi * R + fj] = sCalc[c];
    }
}

extern "C" void kernel_launch(void* const* d_in, const int* in_sizes, int n_in,
                              void* d_out, int out_size, void* d_ws, size_t ws_size,
                              hipStream_t stream) {
    const float* W1   = (const float*)d_in[0];
    const float* b1   = (const float*)d_in[1];
    const float* W2   = (const float*)d_in[2];
    const float* b2   = (const float*)d_in[3];
    const float* W3   = (const float*)d_in[4];
    const float* b3   = (const float*)d_in[5];
    const float* bmin = (const float*)d_in[6];
    const float* bmax = (const float*)d_in[7];

    const int N33 = 33 * 33, N513 = 513 * 513;

    float* q0   = (float*)d_ws;
    float* occA = q0 + N33;
    float* occB = occA + N513;
    u8* calcA = (u8*)(occB + N513);
    u8* calcB = calcA + N513;
    float* out = (float*)d_out;

    eval_base<<<5, 512, 0, stream>>>(W1, b1, W2, b2, W3, b3, bmin, bmax, q0);

    level_fused<<<9,   NT, 0, stream>>>(q0,   (const u8*)nullptr, 33,  occA, calcB, 65,
                                        W1, b1, W2, b2, W3, b3, bmin, bmax);
    level_fused<<<25,  NT, 0, stream>>>(occA, calcB, 65,  occB, calcA, 129,
                                        W1, b1, W2, b2, W3, b3, bmin, bmax);
    level_fused<<<81,  NT, 0, stream>>>(occB, calcA, 129, occA, calcB, 257,
                                        W1, b1, W2, b2, W3, b3, bmin, bmax);
    level_fused<<<289, NT, 0, stream>>>(occA, calcB, 257, out,  calcA, 513,
                                        W1, b1, W2, b2, W3, b3, bmin, bmax);
}

// Round 8
// 63.306 us; speedup vs baseline: 4.9960x; 4.9960x over previous
//
#include <hip/hip_runtime.h>

typedef unsigned char u8;
typedef float f32x4 __attribute__((ext_vector_type(4)));
typedef _Float16 f16x8 __attribute__((ext_vector_type(8)));

#define DIM 128
#define TM  256   // points per block (8 waves x 32 points)

__device__ __forceinline__ float fast_tanh(float x) {
    // tanh(x) = 1 - 2/(exp2(2x*log2e)+1); exact +-1 saturation via inf->0
    float e = __builtin_amdgcn_exp2f(x * 2.885390081777927f);
    return 1.0f - 2.0f * __builtin_amdgcn_rcpf(e + 1.0f);
}
__device__ __forceinline__ float fast_sigmoid(float x) {
    float e = __builtin_amdgcn_exp2f(x * -1.4426950408889634f);
    return __builtin_amdgcn_rcpf(1.0f + e);
}

// ---- dense MLP eval of the 513x513 grid only ----
// (coarser grids are exact subsets: u=(j*2^s)/512 == j/(R_l-1), bit-identical)
// 8 waves/block, each wave: 32 points x 128 out-dims, W2^T fp16 in LDS.
__global__ __launch_bounds__(512, 4) void eval_q4(
    const float* __restrict__ W1, const float* __restrict__ b1,
    const float* __restrict__ W2, const float* __restrict__ b2,
    const float* __restrict__ W3, const float* __restrict__ b3,
    const float* __restrict__ bmin, const float* __restrict__ bmax,
    float* __restrict__ q4)
{
    __shared__ __align__(16) _Float16 sW2T[DIM * DIM];   // 32 KB

    const int R = 513;
    const int N = R * R;                 // 263169
    const int tid = threadIdx.x;
    const int m0 = blockIdx.x * TM;

    // ---- stage W2T into LDS (fp16, XOR-swizzled 16B chunks) ----
    #pragma unroll
    for (int s = 0; s < 4; ++s) {
        int chunk = s * 512 + tid;       // 0..2047
        int n = chunk & 127, ko = chunk >> 7;
        f16x8 v;
        #pragma unroll
        for (int qq = 0; qq < 8; ++qq)
            v[qq] = (_Float16)W2[(ko * 8 + qq) * DIM + n];   // coalesced over n
        int slot = ko ^ (n & 15);
        *(f16x8*)&sW2T[n * DIM + slot * 8] = v;
    }

    const int w = tid >> 6, lane = tid & 63;
    const int l15 = lane & 15, lg = lane >> 4;

    const float inv = 1.0f / 512.0f;     // exact
    const float bx0 = bmin[0], by0 = bmin[1];
    const float sx = bmax[0] - bx0, sy = bmax[1] - by0;
    float xs[2], ys[2];
    #pragma unroll
    for (int mf = 0; mf < 2; ++mf) {
        int pi = m0 + w * 32 + mf * 16 + l15;
        int pg = (pi < N) ? pi : N - 1;
        int gi = pg / R, gj = pg - gi * R;
        xs[mf] = bx0 + (float)gj * inv * sx;
        ys[mf] = by0 + (float)gi * inv * sy;
    }

    f32x4 acc[2][8];
    #pragma unroll
    for (int mf = 0; mf < 2; ++mf)
        #pragma unroll
        for (int nf = 0; nf < 8; ++nf) acc[mf][nf] = (f32x4)(0.0f);

    __syncthreads();

    #pragma unroll
    for (int kf = 0; kf < 4; ++kf) {
        const int kbase = kf * 32 + lg * 8;
        f16x8 bh[8];
        #pragma unroll
        for (int nf = 0; nf < 8; ++nf) {
            int c = nf * 16 + l15;
            int slot = (kf * 4 + lg) ^ l15;   // matches write swizzle (c&15==l15)
            bh[nf] = *(const f16x8*)&sW2T[c * DIM + slot * 8];
        }
        f32x4 wxa = *(const f32x4*)&W1[kbase];
        f32x4 wxb = *(const f32x4*)&W1[kbase + 4];
        f32x4 wya = *(const f32x4*)&W1[DIM + kbase];
        f32x4 wyb = *(const f32x4*)&W1[DIM + kbase + 4];
        f32x4 b1a = *(const f32x4*)&b1[kbase];
        f32x4 b1b = *(const f32x4*)&b1[kbase + 4];
        f16x8 ah[2];
        #pragma unroll
        for (int mf = 0; mf < 2; ++mf) {
            float x = xs[mf], y = ys[mf];
            #pragma unroll
            for (int qq = 0; qq < 4; ++qq)
                ah[mf][qq] = (_Float16)fast_tanh(fmaf(x, wxa[qq], fmaf(y, wya[qq], b1a[qq])));
            #pragma unroll
            for (int qq = 0; qq < 4; ++qq)
                ah[mf][4 + qq] = (_Float16)fast_tanh(fmaf(x, wxb[qq], fmaf(y, wyb[qq], b1b[qq])));
        }
        #pragma unroll
        for (int nf = 0; nf < 8; ++nf)
            #pragma unroll
            for (int mf = 0; mf < 2; ++mf)
                acc[mf][nf] = __builtin_amdgcn_mfma_f32_16x16x32_f16(ah[mf], bh[nf], acc[mf][nf], 0, 0, 0);
    }

    // epilogue in registers; C/D: row = w*32+mf*16+lg*4+rg, col = nf*16+l15
    float rs[2][4] = {{0,0,0,0},{0,0,0,0}};
    #pragma unroll
    for (int nf = 0; nf < 8; ++nf) {
        int c = nf * 16 + l15;
        float w3v = W3[c], b2v = b2[c];
        #pragma unroll
        for (int mf = 0; mf < 2; ++mf)
            #pragma unroll
            for (int rg = 0; rg < 4; ++rg)
                rs[mf][rg] += fast_tanh(acc[mf][nf][rg] + b2v) * w3v;
    }
    #pragma unroll
    for (int mf = 0; mf < 2; ++mf)
        #pragma unroll
        for (int rg = 0; rg < 4; ++rg) {
            float v = rs[mf][rg];
            v += __shfl_xor(v, 1);
            v += __shfl_xor(v, 2);
            v += __shfl_xor(v, 4);
            v += __shfl_xor(v, 8);
            rs[mf][rg] = v;
        }
    if (l15 == 0) {
        float b3v = b3[0];
        #pragma unroll
        for (int mf = 0; mf < 2; ++mf)
            #pragma unroll
            for (int rg = 0; rg < 4; ++rg) {
                int po = m0 + w * 32 + mf * 16 + lg * 4 + rg;
                if (po < N) q4[po] = fast_sigmoid(rs[mf][rg] + b3v);
            }
    }
}

// ---- per level: upsample + raw + boundary + 3 conflict iters, tiled in LDS ----
// occP read via (opRow,opCol) strides; q read from q4 via (qRow,qCol) strides.
// Early-exit: tiles with no raw boundary bits are pure write-through.
#define NT 512
template<int TS>
__global__ __launch_bounds__(NT) void level_kernel(
    const float* __restrict__ occP, int opRow, int opCol,
    const u8* __restrict__ calcP, int Rp,
    const float* __restrict__ q4, int qRow, int qCol,
    float* __restrict__ occOut, u8* __restrict__ calcOut, int R)
{
    constexpr int HW = TS + 8;
    __shared__ float sOcc[HW * HW], sQ[HW * HW];
    __shared__ u8 sRaw[HW * HW], sCalc[HW * HW], sCfA[HW * HW], sCfB[HW * HW];
    const int nT = (R + TS - 1) / TS;
    const int bi = blockIdx.x / nT, bj = blockIdx.x - bi * nT;
    const int fi0 = bi * TS - 4, fj0 = bj * TS - 4;
    const int tid = threadIdx.x;
    const float BAL = 0.5f;

    // phase 1: occ-interp + raw + inherited calc + strided q
    bool anyRaw = false;
    for (int c = tid; c < HW * HW; c += NT) {
        int li = c / HW, lj = c - li * HW;
        int fi = fi0 + li, fj = fj0 + lj;
        float occi = 0.5f, qv = 0.5f; u8 rw = 0, cal = 0;
        if (fi >= 0 && fi < R && fj >= 0 && fj < R) {
            int ip = fi >> 1, jp = fj >> 1;
            float tl = occP[ip * opRow + jp * opCol];
            int oi = fi & 1, oj = fj & 1;
            bool b;
            if (!oi && !oj) { occi = tl; b = false; }
            else if (oi && !oj) {
                float bl = occP[(ip + 1) * opRow + jp * opCol];
                occi = 0.5f * (tl + bl);
                b = (tl > BAL) != (bl > BAL);
            } else if (!oi && oj) {
                float tr = occP[ip * opRow + (jp + 1) * opCol];
                occi = 0.5f * (tl + tr);
                b = (tl > BAL) != (tr > BAL);
            } else {
                float bl = occP[(ip + 1) * opRow + jp * opCol];
                float tr = occP[ip * opRow + (jp + 1) * opCol];
                float br = occP[(ip + 1) * opRow + (jp + 1) * opCol];
                occi = 0.5f * (0.5f * (tl + bl) + 0.5f * (tr + br)); // exact _up2 order
                bool m0 = tl > BAL, m1 = bl > BAL, m2 = tr > BAL, m3 = br > BAL;
                b = (m0 | m1 | m2 | m3) && !(m0 & m1 & m2 & m3);
            }
            rw = b ? 1 : 0;
            if (((fi | fj) & 1) == 0) cal = calcP ? calcP[ip * Rp + jp] : 1;
            qv = q4[fi * qRow + fj * qCol];
        }
        sOcc[c] = occi; sQ[c] = qv; sRaw[c] = rw; sCalc[c] = cal;
        sCfA[c] = 0; sCfB[c] = 0;
        anyRaw |= (rw != 0);
    }

    if (__syncthreads_or(anyRaw ? 1 : 0)) {
        // phase 2: boundary = any3x3(raw) & ~calc; seed conflicts; occ select
        bool anyCf = false;
        for (int c = tid; c < HW * HW; c += NT) {
            int li = c / HW, lj = c - li * HW;
            if (li < 1 || li >= HW - 1 || lj < 1 || lj >= HW - 1) continue;
            int fi = fi0 + li, fj = fj0 + lj;
            if (fi < 0 || fi >= R || fj < 0 || fj >= R) continue;
            bool b = false;
            #pragma unroll
            for (int di = -1; di <= 1; ++di)
                #pragma unroll
                for (int dj = -1; dj <= 1; ++dj)
                    if (sRaw[(li + di) * HW + (lj + dj)]) b = true;
            b = b && !sCalc[c];
            float oi = sOcc[c], qq = sQ[c];
            u8 cf = (b && (oi - BAL) * (qq - BAL) < 0.0f) ? 1 : 0;
            if (b) { sOcc[c] = qq; sCalc[c] = 1; }
            sCfA[c] = cf;
            anyCf |= (cf != 0);
        }
        int haveCf = __syncthreads_or(anyCf ? 1 : 0);

        // 3 conflict-propagation iterations (skip when none remain)
        for (int it = 0; it < 3 && haveCf; ++it) {
            const u8* cin = (it & 1) ? sCfB : sCfA;
            u8* cout      = (it & 1) ? sCfA : sCfB;
            int lo = 2 + it, hi = HW - 2 - it;
            bool anyNc = false;
            for (int c = tid; c < HW * HW; c += NT) {
                int li = c / HW, lj = c - li * HW;
                if (li < lo || li >= hi || lj < lo || lj >= hi) continue;
                int fi = fi0 + li, fj = fj0 + lj;
                if (fi < 0 || fi >= R || fj < 0 || fj >= R) continue;
                bool any = false;
                #pragma unroll
                for (int di = -1; di <= 1; ++di)
                    #pragma unroll
                    for (int dj = -1; dj <= 1; ++dj)
                        if (cin[(li + di) * HW + (lj + dj)]) any = true;
                bool cand = any && !sCalc[c];
                float oc = sOcc[c], qq = sQ[c];
                u8 nc = (cand && (oc - BAL) * (qq - BAL) < 0.0f) ? 1 : 0;
                if (cand) { sOcc[c] = qq; sCalc[c] = 1; }
                cout[c] = nc;
                anyNc |= (nc != 0);
            }
            haveCf = __syncthreads_or(anyNc ? 1 : 0);
        }
    }

    // write core TSxTS (synchronized by the last __syncthreads_or on all paths)
    for (int c = tid; c < HW * HW; c += NT) {
        int li = c / HW, lj = c - li * HW;
        if (li < 4 || li >= HW - 4 || lj < 4 || lj >= HW - 4) continue;
        int fi = fi0 + li, fj = fj0 + lj;
        if (fi < 0 || fi >= R || fj < 0 || fj >= R) continue;
        occOut[fi * R + fj] = sOcc[c];
        calcOut[fi * R + fj] = sCalc[c];
    }
}

extern "C" void kernel_launch(void* const* d_in, const int* in_sizes, int n_in,
                              void* d_out, int out_size, void* d_ws, size_t ws_size,
                              hipStream_t stream) {
    const float* W1   = (const float*)d_in[0];
    const float* b1   = (const float*)d_in[1];
    const float* W2   = (const float*)d_in[2];
    const float* b2   = (const float*)d_in[3];
    const float* W3   = (const float*)d_in[4];
    const float* b3   = (const float*)d_in[5];
    const float* bmin = (const float*)d_in[6];
    const float* bmax = (const float*)d_in[7];

    const int RF = 513, N513 = RF * RF;

    float* q4   = (float*)d_ws;
    float* occA = q4 + N513;
    float* occB = occA + N513;
    u8* calcA = (u8*)(occB + N513);
    u8* calcB = calcA + N513;
    float* out = (float*)d_out;

    // dense eval of the 513 grid only; 1029 blocks x 256 points
    eval_q4<<<(N513 + TM - 1) / TM, 512, 0, stream>>>(
        W1, b1, W2, b2, W3, b3, bmin, bmax, q4);

    // level 1 (R=65): occP = q4 stride 16 (the 33-grid), calc all-true
    level_kernel<8><<<81, NT, 0, stream>>>(
        q4, RF * 16, 16, (const u8*)nullptr, 33,
        q4, RF * 8, 8, occA, calcB, 65);
    // level 2 (R=129): q stride 4
    level_kernel<16><<<81, NT, 0, stream>>>(
        occA, 65, 1, calcB, 65,
        q4, RF * 4, 4, occB, calcA, 129);
    // level 3 (R=257): q stride 2
    level_kernel<32><<<81, NT, 0, stream>>>(
        occB, 129, 1, calcA, 129,
        q4, RF * 2, 2, occA, calcB, 257);
    // level 4 (R=513): q stride 1
    level_kernel<32><<<289, NT, 0, stream>>>(
        occA, 257, 1, calcB, 257,
        q4, RF, 1, out, calcA, 513);
}